// Round 10
// baseline (150.221 us; speedup 1.0000x reference)
//
#include <hip/hip_runtime.h>
#include <stdint.h>

// Problem constants
#define B_SZ   1024
#define GF     512
#define GC     63
#define NLEAF  64
#define IN_F   512
#define OUT_F  512

typedef float f32x4 __attribute__((ext_vector_type(4)));
typedef __fp16 h16x2 __attribute__((ext_vector_type(2)));
typedef __fp16 h16x8 __attribute__((ext_vector_type(8)));
typedef _Float16 f16x2 __attribute__((ext_vector_type(2)));
typedef unsigned short ushort;

union HF8 { f16x2 h2[4]; h16x8 v; uint4 u; };
union HU  { ushort u; _Float16 f; };

__device__ inline f16x2 pkrtz(float a, float b) {
  union { h16x2 r; f16x2 f; } u;
  u.r = __builtin_amdgcn_cvt_pkrtz(a, b);
  return u.f;
}

// ---------------------------------------------------------------------------
// Kernel 1: gatings = sigmoid(x_gating @ gw + gb); leaf_probs tree product.
// (unchanged — proven)
// ---------------------------------------------------------------------------
__global__ __launch_bounds__(512, 2) void k_leafprobs(
    const float* __restrict__ xg, const float* __restrict__ gw,
    const float* __restrict__ gb, float* __restrict__ p_ws)
{
  __shared__ float xsr[GF];
  __shared__ float part[512];
  __shared__ float gates[GC + 1];
  const int b = blockIdx.x;
  const int t = threadIdx.x;

  xsr[t] = xg[(size_t)b * GF + t];
  __syncthreads();

  const int ks = t >> 6, g = t & 63;
  float acc = 0.f;
  if (g < GC) {
    const float* gp = gw + (size_t)(ks * 64) * GC + g;
    const float* xp = &xsr[ks * 64];
#pragma unroll 8
    for (int k = 0; k < 64; ++k) acc += xp[k] * gp[(size_t)k * GC];
  }
  part[t] = acc;
  __syncthreads();

  if (t < GC) {
    float s = gb[t];
#pragma unroll
    for (int r = 0; r < 8; ++r) s += part[r * 64 + t];
    gates[t] = 1.f / (1.f + expf(-s));
  }
  __syncthreads();

  if (t < NLEAF) {
    float v = 1.f;
    int idx = 0, start = 0;
#pragma unroll
    for (int d = 0; d < 6; ++d) {
      int bit = (t >> (5 - d)) & 1;
      float gg = gates[start + idx];
      v *= bit ? (1.f - gg) : gg;
      idx = 2 * idx + bit;
      start += (1 << d);
    }
    p_ws[(size_t)b * NLEAF + t] = v;
  }
}

// ---------------------------------------------------------------------------
// Kernel 2 (FUSED): R8 base (best: 47.5us) + anti-lockstep changes:
// R9 diagnosis: MFMA(1024) + VALU(1036) + LDS(~1200) cyc/CU/i-step run
// SERIALLY (sum == measured 3700) — barrier-aligned waves burst each pipe
// in phase. Levers:
//  (1) s_setprio REMOVED (m190: hurts lockstep GEMM — enforces the convoy)
//  (2) barrier cadence 2 -> 3 i-steps (16 -> 11 barriers): bs[2][3][8KB],
//      rb 6 slots. vmcnt ledger: steady stage-wait = 20 (6 tiles/24 loads
//      in flight); drain 16/12/8 then 4/0; slot = tile%6, refill after
//      stage lands in the just-freed slot.
//  (3) xs stored f16 (16KB; same rounding point as the old (_Float16)x
//      cast -> bit-identical) so LDS stays 64KB -> 2 blocks/CU.
// pb fold kept (kc==0), now staged into buf1 (tail computes read buf0).
// ---------------------------------------------------------------------------
#define SK 16
#define KI 32   // 512 / SK

template <bool ATOMIC>
__global__ __launch_bounds__(256, 2) void k_fused(
    const float* __restrict__ x_leaf,   // [1024][512]
    const float* __restrict__ p_ws,     // [1024][64]
    const float* __restrict__ pw,       // [512][512][64]  ([o][i][l])
    const float* __restrict__ pb,       // [512][64]
    float* __restrict__ dst)            // parts [SK][1024][512] or out
{
  __shared__ __align__(16) ushort        xs_h[KI][256];   // 16 KB f16 (transposed)
  __shared__ __align__(16) unsigned char bs8[2 * 24576];  // 2buf x 3sub x 8KB

  const int tid  = threadIdx.x;
  const int lane = tid & 63;
  const int wid  = tid >> 6;        // 0..3
  const int quad = lane >> 4;
  const int l15  = lane & 15;
  const int l7   = l15 & 7;

  const int bid = blockIdx.x;       // 512
  const int nt  = bid & 7;
  const int mt  = (bid >> 3) & 3;
  const int kc  = bid >> 5;         // 0..15

  const int row_m0 = mt * 256;
  const int o0     = nt * 64;
  const int i0     = kc * KI;
  const int wm     = wid * 64;      // 64 rows per wave

  // ---- stage x slab transposed f16 [KI][256]: one row per thread ----
  {
    const float* src = x_leaf + (size_t)(row_m0 + tid) * IN_F + i0;
#pragma unroll
    for (int q = 0; q < 8; ++q) {
      float4 v = *(const float4*)(src + q * 4);
      HU t0, t1, t2, t3;
      t0.f = (_Float16)v.x; t1.f = (_Float16)v.y;
      t2.f = (_Float16)v.z; t3.f = (_Float16)v.w;
      xs_h[q * 4 + 0][tid] = t0.u;
      xs_h[q * 4 + 1][tid] = t1.u;
      xs_h[q * 4 + 2][tid] = t2.u;
      xs_h[q * 4 + 3][tid] = t3.u;
    }
  }

  // ---- p fragments, converted ONCE to f16 (reused all K) ----
  HF8 prh[4][2];
#pragma unroll
  for (int mi = 0; mi < 4; ++mi) {
    const int row = row_m0 + wm + mi * 16 + l15;
#pragma unroll
    for (int ks = 0; ks < 2; ++ks) {
      const f32x4* src = (const f32x4*)(p_ws + (size_t)row * NLEAF + ks * 32 + quad * 8);
      f32x4 lo = src[0], hi = src[1];
      prh[mi][ks].h2[0] = pkrtz(lo[0], lo[1]);
      prh[mi][ks].h2[1] = pkrtz(lo[2], lo[3]);
      prh[mi][ks].h2[2] = pkrtz(hi[0], hi[1]);
      prh[mi][ks].h2[3] = pkrtz(hi[2], hi[3]);
    }
  }

  // ---- B-load geometry: thread = (br = tid>>2 of 64 o-rows, seg = tid&3) ----
  const int br  = tid >> 2;
  const int seg = tid & 3;
  const float* bsrc0 = pw + ((size_t)(o0 + br) * IN_F + i0) * NLEAF + seg * 16;

  // swizzled LDS offsets (XOR in byte bits 4-6; fields don't carry)
  const int wsw   = (br & 7) << 4;
  const int woff0 = br * 128 + ((seg * 32) ^ wsw);
  const int woff1 = br * 128 + ((seg * 32 + 16) ^ wsw);
  int coff[2];
#pragma unroll
  for (int ks = 0; ks < 2; ++ks)
    coff[ks] = (ks * 64 + quad * 16) ^ (l7 << 4);
  const int rbase = l15 * 128;

  f32x4 acc[4][4];
#pragma unroll
  for (int mi = 0; mi < 4; ++mi)
#pragma unroll
    for (int ni = 0; ni < 4; ++ni)
      acc[mi][ni] = (f32x4)(0.f);

  f32x4 rb[6][4];   // 6-slot register prefetch (tile T -> slot T%6)

  // volatile asm loads; "=&v" early-clobber (R5 lesson).
#define BLOAD(T, SLOT)                                                        \
  {                                                                           \
    const float* a_ = bsrc0 + (size_t)(T) * NLEAF;                            \
    asm volatile(                                                             \
        "global_load_dwordx4 %0, %4, off\n\t"                                 \
        "global_load_dwordx4 %1, %4, off offset:16\n\t"                       \
        "global_load_dwordx4 %2, %4, off offset:32\n\t"                       \
        "global_load_dwordx4 %3, %4, off offset:48"                           \
        : "=&v"(rb[SLOT][0]), "=&v"(rb[SLOT][1]),                             \
          "=&v"(rb[SLOT][2]), "=&v"(rb[SLOT][3])                              \
        : "v"(a_) : "memory");                                                \
  }

  // counted wait tied to the slot's regs (SSA deps keep consumers below).
#define BWAIT_(SLOT, N)                                                       \
  asm volatile("s_waitcnt vmcnt(" #N ")"                                      \
               : "+v"(rb[SLOT][0]), "+v"(rb[SLOT][1]),                        \
                 "+v"(rb[SLOT][2]), "+v"(rb[SLOT][3])::"memory");
#define BWAIT(SLOT, N) BWAIT_(SLOT, N)

#define BSTAGE(SLOT, BUF, SUB)                                                \
  {                                                                           \
    HF8 c0_, c1_;                                                             \
    f32x4 a0_ = rb[SLOT][0], a1_ = rb[SLOT][1];                               \
    f32x4 a2_ = rb[SLOT][2], a3_ = rb[SLOT][3];                               \
    c0_.h2[0] = pkrtz(a0_[0], a0_[1]);                                        \
    c0_.h2[1] = pkrtz(a0_[2], a0_[3]);                                        \
    c0_.h2[2] = pkrtz(a1_[0], a1_[1]);                                        \
    c0_.h2[3] = pkrtz(a1_[2], a1_[3]);                                        \
    c1_.h2[0] = pkrtz(a2_[0], a2_[1]);                                        \
    c1_.h2[1] = pkrtz(a2_[2], a2_[3]);                                        \
    c1_.h2[2] = pkrtz(a3_[0], a3_[1]);                                        \
    c1_.h2[3] = pkrtz(a3_[2], a3_[3]);                                        \
    unsigned char* d_ = bs8 + (BUF) * 24576 + (SUB) * 8192;                   \
    *(uint4*)(d_ + woff0) = c0_.u;                                            \
    *(uint4*)(d_ + woff1) = c1_.u;                                            \
  }

  // lgkm-only barrier — global prefetch stays in flight across it.
#define BARRIER() asm volatile("s_waitcnt lgkmcnt(0)\n\ts_barrier" ::: "memory")

#define COMPUTE(IT, BUF, SUB)                                                 \
  {                                                                           \
    _Float16 xh[4];                                                           \
    _Pragma("unroll")                                                         \
    for (int mi = 0; mi < 4; ++mi) {                                          \
      HU t_; t_.u = xs_h[(IT)][wm + mi * 16 + l15]; xh[mi] = t_.f;            \
    }                                                                         \
    const unsigned char* bsr_ = bs8 + (BUF) * 24576 + (SUB) * 8192;           \
    _Pragma("unroll")                                                         \
    for (int ks = 0; ks < 2; ++ks) {                                          \
      h16x8 af[4];                                                            \
      _Pragma("unroll")                                                       \
      for (int mi = 0; mi < 4; ++mi) {                                        \
        HF8 t_;                                                               \
        f16x2 xp_; xp_[0] = xh[mi]; xp_[1] = xh[mi];                          \
        _Pragma("unroll")                                                     \
        for (int j = 0; j < 4; ++j) t_.h2[j] = prh[mi][ks].h2[j] * xp_;       \
        af[mi] = t_.v;                                                        \
      }                                                                       \
      _Pragma("unroll")                                                       \
      for (int ni = 0; ni < 4; ++ni) {                                        \
        h16x8 bfr = *(const h16x8*)(bsr_ + ni * 2048 + rbase + coff[ks]);     \
        _Pragma("unroll")                                                     \
        for (int mi = 0; mi < 4; ++mi)                                        \
          acc[mi][ni] = __builtin_amdgcn_mfma_f32_16x16x32_f16(               \
              af[mi], bfr, acc[mi][ni], 0, 0, 0);                             \
      }                                                                       \
    }                                                                         \
  }

// Phase p (3 i-steps): compute tiles {IT0..IT0+2} from bs[BUF]; stage tiles
// {IT0+3..IT0+5} (slots SB..SB+2) into bs[BUF^1]; load {IT0+9..IT0+11} into
// the just-freed slots. One barrier per phase.
#define PHASE(IT0, BUF, SB, W1, W2, W3, D1, D2, D3)                           \
  {                                                                           \
    COMPUTE(IT0, BUF, 0)                                                      \
    BWAIT(SB, W1)                                                             \
    BSTAGE(SB, (BUF) ^ 1, 0)                                                  \
    if (D1) { BLOAD((IT0) + 9, SB) }                                          \
    COMPUTE((IT0) + 1, BUF, 1)                                                \
    BWAIT((SB) + 1, W2)                                                       \
    BSTAGE((SB) + 1, (BUF) ^ 1, 1)                                            \
    if (D2) { BLOAD((IT0) + 10, (SB) + 1) }                                   \
    COMPUTE((IT0) + 2, BUF, 2)                                                \
    BWAIT((SB) + 2, W3)                                                       \
    BSTAGE((SB) + 2, (BUF) ^ 1, 2)                                            \
    if (D3) { BLOAD((IT0) + 11, (SB) + 2) }                                   \
    BARRIER();                                                                \
  }

  // ---- prologue: tiles 0..5 issued; stage 0,1,2 -> buf0; issue 6,7,8 ----
  BLOAD(0, 0)
  BLOAD(1, 1)
  BLOAD(2, 2)
  BLOAD(3, 3)
  BLOAD(4, 4)
  BLOAD(5, 5)
  BWAIT(0, 20)
  BSTAGE(0, 0, 0)
  BLOAD(6, 0)
  BWAIT(1, 20)
  BSTAGE(1, 0, 1)
  BLOAD(7, 1)
  BWAIT(2, 20)
  BSTAGE(2, 0, 2)
  BLOAD(8, 2)
  BARRIER();         // xs + bs[0] visible; tiles {3..8} in flight

  // ---- phases p=0..8 ----
  PHASE(0,  0, 3, 20, 20, 20, 1, 1, 1)
  PHASE(3,  1, 0, 20, 20, 20, 1, 1, 1)
  PHASE(6,  0, 3, 20, 20, 20, 1, 1, 1)
  PHASE(9,  1, 0, 20, 20, 20, 1, 1, 1)
  PHASE(12, 0, 3, 20, 20, 20, 1, 1, 1)
  PHASE(15, 1, 0, 20, 20, 20, 1, 1, 1)
  PHASE(18, 0, 3, 20, 20, 20, 1, 1, 1)
  PHASE(21, 1, 0, 20, 20, 20, 1, 1, 0)   // loads tiles 30,31
  PHASE(24, 0, 3, 16, 12, 8, 0, 0, 0)    // drain begins
  // ---- p9: compute {27,28,29} from buf1; stage 30,31 -> buf0 ----
  COMPUTE(27, 1, 0)
  BWAIT(0, 4)
  BSTAGE(0, 0, 0)
  COMPUTE(28, 1, 1)
  BWAIT(1, 0)
  BSTAGE(1, 0, 1)
  COMPUTE(29, 1, 2)
  BARRIER();
  // ---- tail: compute 30,31 from buf0 ----
  COMPUTE(30, 0, 0)
  COMPUTE(31, 0, 1)

#undef BLOAD
#undef BWAIT
#undef BWAIT_
#undef BSTAGE
#undef BARRIER
#undef COMPUTE
#undef PHASE

  // ---- pb fold: kc==0 blocks add p @ pb^T via one pseudo-i-step.
  // Staged into BUF1 sub0: last buf1 reads ended at p9's BARRIER (tail
  // computes read buf0), so no wave can still be reading buf1.
  if (kc == 0) {
    {
      const float* pbs = pb + (size_t)(o0 + br) * NLEAF + seg * 16;
      float4 a0_ = *(const float4*)(pbs);
      float4 a1_ = *(const float4*)(pbs + 4);
      float4 a2_ = *(const float4*)(pbs + 8);
      float4 a3_ = *(const float4*)(pbs + 12);
      HF8 c0_, c1_;
      c0_.h2[0] = pkrtz(a0_.x, a0_.y);
      c0_.h2[1] = pkrtz(a0_.z, a0_.w);
      c0_.h2[2] = pkrtz(a1_.x, a1_.y);
      c0_.h2[3] = pkrtz(a1_.z, a1_.w);
      c1_.h2[0] = pkrtz(a2_.x, a2_.y);
      c1_.h2[1] = pkrtz(a2_.z, a2_.w);
      c1_.h2[2] = pkrtz(a3_.x, a3_.y);
      c1_.h2[3] = pkrtz(a3_.z, a3_.w);
      *(uint4*)(bs8 + 24576 + woff0) = c0_.u;
      *(uint4*)(bs8 + 24576 + woff1) = c1_.u;
    }
    __syncthreads();
    const unsigned char* bsr_ = bs8 + 24576;
#pragma unroll
    for (int ks = 0; ks < 2; ++ks) {
#pragma unroll
      for (int ni = 0; ni < 4; ++ni) {
        h16x8 bfr = *(const h16x8*)(bsr_ + ni * 2048 + rbase + coff[ks]);
#pragma unroll
        for (int mi = 0; mi < 4; ++mi)
          acc[mi][ni] = __builtin_amdgcn_mfma_f32_16x16x32_f16(
              prh[mi][ks].v, bfr, acc[mi][ni], 0, 0, 0);
      }
    }
  }

  // ---- epilogue ----
#pragma unroll
  for (int mi = 0; mi < 4; ++mi) {
#pragma unroll
    for (int ni = 0; ni < 4; ++ni) {
      int row = row_m0 + wm + mi * 16 + quad * 4;
      int col = o0 + ni * 16 + l15;
      if (ATOMIC) {
        float* o = dst + (size_t)row * OUT_F + col;
        atomicAdd(o,             acc[mi][ni][0]);
        atomicAdd(o + OUT_F,     acc[mi][ni][1]);
        atomicAdd(o + 2 * OUT_F, acc[mi][ni][2]);
        atomicAdd(o + 3 * OUT_F, acc[mi][ni][3]);
      } else {
        float* o = dst + ((size_t)kc << 19) + (size_t)row * OUT_F + col;
        o[0]         = acc[mi][ni][0];
        o[OUT_F]     = acc[mi][ni][1];
        o[2 * OUT_F] = acc[mi][ni][2];
        o[3 * OUT_F] = acc[mi][ni][3];
      }
    }
  }
}

// ---------------------------------------------------------------------------
// Kernel 3 (slim): out = sum_kc parts[kc]  (pb handled in k_fused).
// nparts==0 -> zero-init for the atomic fallback.
// ---------------------------------------------------------------------------
__global__ __launch_bounds__(256, 8) void k_reduce(
    const float* __restrict__ parts, float* __restrict__ out, int nparts)
{
  const int idx = blockIdx.x * 256 + threadIdx.x;   // f32x4 index, 131072 total
  f32x4 a = (f32x4)(0.f);
#pragma unroll 8
  for (int k = 0; k < nparts; ++k)
    a += ((const f32x4*)(parts + ((size_t)k << 19)))[idx];
  ((f32x4*)out)[idx] = a;
}

// ---------------------------------------------------------------------------
extern "C" void kernel_launch(void* const* d_in, const int* in_sizes, int n_in,
                              void* d_out, int out_size, void* d_ws, size_t ws_size,
                              hipStream_t stream) {
  const float* xg = (const float*)d_in[0];   // x_gating [1024][512]
  const float* xl = (const float*)d_in[1];   // x_leaf   [1024][512]
  const float* gw = (const float*)d_in[2];   // [512][63]
  const float* gb = (const float*)d_in[3];   // [63]
  const float* pw = (const float*)d_in[4];   // [512][512][64]
  const float* pb = (const float*)d_in[5];   // [512][64]
  float* out = (float*)d_out;

  // ws: p fp32 (256 KB) | parts fp32 [SK][1024][512] (32 MB)
  const size_t P_BYTES = (size_t)B_SZ * NLEAF * 4;
  const size_t SLICE   = (size_t)B_SZ * OUT_F * 4;

  float* p_ws  = (float*)d_ws;
  float* parts = (float*)((char*)d_ws + P_BYTES);

  k_leafprobs<<<dim3(B_SZ), dim3(512), 0, stream>>>(xg, gw, gb, p_ws);

  if (ws_size >= P_BYTES + SK * SLICE) {
    k_fused<false><<<dim3(512), dim3(256), 0, stream>>>(xl, p_ws, pw, pb, parts);
    k_reduce<<<dim3(512), dim3(256), 0, stream>>>(parts, out, SK);
  } else {
    k_reduce<<<dim3(512), dim3(256), 0, stream>>>(parts, out, 0);
    k_fused<true><<<dim3(512), dim3(256), 0, stream>>>(xl, p_ws, pw, pb, out);
  }
}